// Round 1
// baseline (76.742 us; speedup 1.0000x reference)
//
#include <hip/hip_runtime.h>

// MPDNN: SchNet-style MPNN. Key ideas:
//  - Wf[b,i,j,:] depends only on d(i,j) -> 4096-entry fp32 lookup table (no [B,N,N,F] tensor)
//  - compact neighbor lists (d<6, ~25% density), entry = j | (table_idx<<7), padded to x4
//  - c_aniso.sum(j) pushed through the linear @We2
//  - per-block row-batched matvecs so Wu/Wp/We weights are read once per block
// ws layout (floats): table[4097*128] | h_a[2048*128] | h_b | pre_i | pre_j | ent(u32) | cnt(i32)

#define LN2F 0.69314718055994531f

__device__ __forceinline__ float sspf(float x) {          // softplus(x) - ln2, stable
  float e = __expf(-fabsf(x));
  return fmaxf(x, 0.0f) + __logf(1.0f + e) - LN2F;
}
__device__ __forceinline__ unsigned int f2bf(float x) {   // fp32 -> bf16 bits (RNE)
  unsigned int u = __float_as_uint(x);
  return (u + 0x7fffu + ((u >> 16) & 1u)) >> 16;
}
__device__ __forceinline__ float bflo(unsigned int u) { return __uint_as_float(u << 16); }
__device__ __forceinline__ float bfhi(unsigned int u) { return __uint_as_float(u & 0xffff0000u); }

// ---------------------------------------------------------------------------
// prep: blocks [0,1024): neighbor lists + embedding (2 nodes/block)
//       blocks [1024,1280): filter table, 16 d-samples/block
// ---------------------------------------------------------------------------
__global__ __launch_bounds__(256) void prep_kernel(
    const float* __restrict__ coords, const int* __restrict__ species,
    const float* __restrict__ emb,
    const float* __restrict__ Wc1, const float* __restrict__ bc1,
    const float* __restrict__ Wc2, const float* __restrict__ bc2,
    float* __restrict__ table, float* __restrict__ h_a,
    unsigned int* __restrict__ ent, int* __restrict__ cnt) {
  int t = threadIdx.x;
  if (blockIdx.x < 1024) {
    __shared__ int wc[4];
    int node = blockIdx.x * 2 + (t >> 7);
    int j = t & 127;
    int b = node >> 7, i = node & 127;
    float cix = coords[node*3+0], ciy = coords[node*3+1], ciz = coords[node*3+2];
    int jn = b*128 + j;
    float dx = cix - coords[jn*3+0];
    float dy = ciy - coords[jn*3+1];
    float dz = ciz - coords[jn*3+2];
    float d2 = dx*dx + dy*dy + dz*dz;
    float d  = sqrtf(d2);
    bool valid = (d < 6.0f) && (j != i);
    int k = 4096;                                   // 4096 = zero row (pad)
    if (valid) {
      k = (int)(d * (4096.0f / 6.0f));
      if (k > 4095) k = 4095;
    }
    unsigned long long bal = __ballot(valid);
    int lane = t & 63, w = t >> 6;
    if (lane == 0) wc[w] = (int)__popcll(bal);
    __syncthreads();
    int nloc = t >> 7;
    int nn = wc[2*nloc] + wc[2*nloc+1];
    int base = ((w & 1) ? wc[w-1] : 0) + (int)__popcll(bal & ((1ull << lane) - 1ull));
    if (valid) ent[node*128 + base] = (unsigned int)(j | (k << 7));
    int nnp = (nn + 3) & ~3;
    if (j >= nn && j < nnp) ent[node*128 + j] = (4096u << 7);   // pad -> zero table row
    if (j == 0) cnt[node] = nn | (nnp << 16);
    h_a[node*128 + j] = emb[species[node]*128 + j];
  } else {
    __shared__ float rbf_all[16][32];
    __shared__ float hid_all[16][128];
    int tb = (int)blockIdx.x - 1024;                // 0..255
    int t0 = tb * 16;
    for (int idx = t; idx < 512; idx += 256) {
      int tt = idx >> 5, kk = idx & 31;
      float d = (float)(t0 + tt) * (6.0f/4096.0f) + 0.5f * (6.0f/4096.0f);
      float mu = 0.5f + (float)kk * (5.5f/31.0f);
      float z = d - mu;
      rbf_all[tt][kk] = __expf(-8.0f * z * z);      // 1/(2*0.25^2)=8
    }
    __syncthreads();
    int f = t & 127, sub = t >> 7;                  // sub handles rows sub*8..+7
    float s[8];
    float b1 = bc1[f];
#pragma unroll
    for (int r = 0; r < 8; r++) s[r] = b1;
    for (int kk = 0; kk < 32; kk++) {
      float wv = Wc1[kk*128 + f];
#pragma unroll
      for (int r = 0; r < 8; r++) s[r] += rbf_all[sub*8 + r][kk] * wv;
    }
#pragma unroll
    for (int r = 0; r < 8; r++) hid_all[sub*8 + r][f] = sspf(s[r]);
    __syncthreads();
    float o[8];
    float b2 = bc2[f];
#pragma unroll
    for (int r = 0; r < 8; r++) o[r] = b2;
    for (int g = 0; g < 128; g++) {
      float wv = Wc2[g*128 + f];
#pragma unroll
      for (int r = 0; r < 8; r++) o[r] += hid_all[sub*8 + r][g] * wv;
    }
#pragma unroll
    for (int r = 0; r < 8; r++) table[(t0 + sub*8 + r)*128 + f] = o[r];
    if (tb == 255 && t < 128) table[4096*128 + t] = 0.0f;      // zero pad row
  }
}

// ---------------------------------------------------------------------------
// conv: one block = 4 nodes of one batch. message (table-gather) + update net.
// ---------------------------------------------------------------------------
__global__ __launch_bounds__(512) void conv_kernel(
    const float* __restrict__ h_cur, float* __restrict__ h_next,
    const float* __restrict__ table, const unsigned int* __restrict__ ent,
    const int* __restrict__ cnt,
    const float* __restrict__ Wu1, const float* __restrict__ bu1,
    const float* __restrict__ Wu2, const float* __restrict__ bu2) {
  __shared__ unsigned int hsh[8192];        // h[b] as bf16x2, [j][fpair], 32 KB
  __shared__ unsigned int ent_s[4][128];
  __shared__ float mred[8][128];
  __shared__ float m_s[4][128];
  __shared__ float red[4][4][128];
  __shared__ float u1_s[4][128];
  __shared__ int nn_s[4];
  int t = threadIdx.x;
  int node0 = blockIdx.x * 4;
  int b = blockIdx.x >> 5;
  const float2* hb = (const float2*)(h_cur + b*16384);
  for (int c = 0; c < 16; c++) {
    int idx = c*512 + t;
    float2 v = hb[idx];
    hsh[idx] = (f2bf(v.y) << 16) | f2bf(v.x);
  }
  { int ii = t >> 7, f = t & 127;
    ent_s[ii][f] = ent[(node0 + ii)*128 + f]; }
  if (t < 4) nn_s[t] = cnt[node0 + t];
  __syncthreads();

  // --- message: wave pair (ii) strides the neighbor list, 2-way unrolled ---
  int w = t >> 6, lane = t & 63;
  int ii = w >> 1, par = w & 1;
  int nnp = nn_s[ii] >> 16;                 // padded count (multiple of 4)
  float a0 = 0.f, a1 = 0.f, c0 = 0.f, c1 = 0.f;
  for (int e = par; e + 2 < nnp; e += 4) {
    unsigned int u0 = ent_s[ii][e], u1 = ent_s[ii][e + 2];
    int j0 = u0 & 127, k0 = (int)(u0 >> 7);
    int j1 = u1 & 127, k1 = (int)(u1 >> 7);
    float2 t0 = *(const float2*)(table + k0*128 + 2*lane);
    float2 t1 = *(const float2*)(table + k1*128 + 2*lane);
    unsigned int h0 = hsh[j0*64 + lane];
    unsigned int h1 = hsh[j1*64 + lane];
    a0 += t0.x * bflo(h0); a1 += t0.y * bfhi(h0);
    c0 += t1.x * bflo(h1); c1 += t1.y * bfhi(h1);
  }
  a0 += c0; a1 += c1;
  *(float2*)&mred[w][2*lane] = make_float2(a0, a1);
  __syncthreads();
  { int i2 = t >> 7, f = t & 127;
    m_s[i2][f] = mred[2*i2][f] + mred[2*i2+1][f]; }
  __syncthreads();

  // --- update net, 4 rows batched per weight load ---
  int g = t & 127, q = t >> 7;
  {
    float p0=0,p1=0,p2=0,p3=0;
    for (int f = q*32; f < q*32 + 32; f++) {
      float wv = Wu1[f*128 + g];
      p0 += m_s[0][f]*wv; p1 += m_s[1][f]*wv; p2 += m_s[2][f]*wv; p3 += m_s[3][f]*wv;
    }
    red[q][0][g]=p0; red[q][1][g]=p1; red[q][2][g]=p2; red[q][3][g]=p3;
  }
  __syncthreads();
  { int i2 = t >> 7, gg = t & 127;
    u1_s[i2][gg] = sspf(red[0][i2][gg]+red[1][i2][gg]+red[2][i2][gg]+red[3][i2][gg] + bu1[gg]); }
  __syncthreads();
  {
    float p0=0,p1=0,p2=0,p3=0;
    for (int f = q*32; f < q*32 + 32; f++) {
      float wv = Wu2[f*128 + g];
      p0 += u1_s[0][f]*wv; p1 += u1_s[1][f]*wv; p2 += u1_s[2][f]*wv; p3 += u1_s[3][f]*wv;
    }
    red[q][0][g]=p0; red[q][1][g]=p1; red[q][2][g]=p2; red[q][3][g]=p3;
  }
  __syncthreads();
  { int i2 = t >> 7, o = t & 127;
    int node = node0 + i2;
    float delta = red[0][i2][o]+red[1][i2][o]+red[2][i2][o]+red[3][i2][o] + bu2[o];
    h_next[node*128 + o] = h_cur[node*128 + o] + delta; }
}

// ---------------------------------------------------------------------------
// pool (blocks<512: c_iso, 4 nodes) + edge_pre (blocks>=512: pre_i/pre_j, 8 rows)
// ---------------------------------------------------------------------------
__global__ __launch_bounds__(256) void poolpre_kernel(
    const float* __restrict__ h,
    const float* __restrict__ Wp1, const float* __restrict__ bp1,
    const float* __restrict__ Wp2, const float* __restrict__ bp2,
    const float* __restrict__ Wei, const float* __restrict__ Wej,
    float* __restrict__ pre_i, float* __restrict__ pre_j,
    float* __restrict__ out) {
  int t = threadIdx.x;
  if (blockIdx.x < 512) {
    __shared__ float hs[4][128];
    __shared__ float redp[4][4][64];
    __shared__ float us[4][64];
    int node0 = blockIdx.x * 4;
    for (int idx = t; idx < 512; idx += 256) hs[idx >> 7][idx & 127] = h[node0*128 + idx];
    __syncthreads();
    int g = t & 63, q = t >> 6;
    float p0=0,p1=0,p2=0,p3=0;
    for (int f = q*32; f < q*32 + 32; f++) {
      float wv = Wp1[f*64 + g];
      p0 += hs[0][f]*wv; p1 += hs[1][f]*wv; p2 += hs[2][f]*wv; p3 += hs[3][f]*wv;
    }
    redp[q][0][g]=p0; redp[q][1][g]=p1; redp[q][2][g]=p2; redp[q][3][g]=p3;
    __syncthreads();
    { int ii = t >> 6, gg = t & 63;
      us[ii][gg] = sspf(redp[0][ii][gg]+redp[1][ii][gg]+redp[2][ii][gg]+redp[3][ii][gg] + bp1[gg]); }
    __syncthreads();
    if (t < 32) {
      int ii = t >> 3, o = t & 7;
      float v = bp2[o];
      for (int gg = 0; gg < 64; gg++) v += us[ii][gg] * Wp2[gg*8 + o];
      out[(node0 + ii)*8 + o] = v;
    }
  } else {
    __shared__ float hs8[8][128];
    int node0 = ((int)blockIdx.x - 512) * 8;
    for (int idx = t; idx < 1024; idx += 256) hs8[idx >> 7][idx & 127] = h[node0*128 + idx];
    __syncthreads();
    int o = t & 127, which = t >> 7;
    const float* W = which ? Wej : Wei;
    float p0=0,p1=0,p2=0,p3=0,p4=0,p5=0,p6=0,p7=0;
    for (int f = 0; f < 128; f++) {
      float wv = W[f*128 + o];
      p0 += hs8[0][f]*wv; p1 += hs8[1][f]*wv; p2 += hs8[2][f]*wv; p3 += hs8[3][f]*wv;
      p4 += hs8[4][f]*wv; p5 += hs8[5][f]*wv; p6 += hs8[6][f]*wv; p7 += hs8[7][f]*wv;
    }
    float* dst = which ? pre_j : pre_i;
    dst[(node0+0)*128+o]=p0; dst[(node0+1)*128+o]=p1; dst[(node0+2)*128+o]=p2; dst[(node0+3)*128+o]=p3;
    dst[(node0+4)*128+o]=p4; dst[(node0+5)*128+o]=p5; dst[(node0+6)*128+o]=p6; dst[(node0+7)*128+o]=p7;
  }
}

// ---------------------------------------------------------------------------
// edgepool: c_aniso_sum[node] = (sum_j ssp(pre_i+pre_j+be1)) @ We2 + be2*nn
// ---------------------------------------------------------------------------
__global__ __launch_bounds__(512) void edgepool_kernel(
    const float* __restrict__ pre_i, const float* __restrict__ pre_j,
    const unsigned int* __restrict__ ent, const int* __restrict__ cnt,
    const float* __restrict__ be1, const float* __restrict__ We2,
    const float* __restrict__ be2, float* __restrict__ out) {
  __shared__ unsigned int pjs[8192];        // pre_j[b] bf16x2, 32 KB
  __shared__ unsigned int ent_s[4][128];
  __shared__ float pis[4][128];
  __shared__ float sred[8][128];
  __shared__ float s_s[4][128];
  __shared__ float r2[4][8][16];
  __shared__ int nn_s[4];
  int t = threadIdx.x;
  int node0 = blockIdx.x * 4;
  int b = blockIdx.x >> 5;
  const float2* pjb = (const float2*)(pre_j + b*16384);
  for (int c = 0; c < 16; c++) {
    int idx = c*512 + t;
    float2 v = pjb[idx];
    pjs[idx] = (f2bf(v.y) << 16) | f2bf(v.x);
  }
  { int ii = t >> 7, f = t & 127;
    pis[ii][f] = pre_i[(node0 + ii)*128 + f];
    ent_s[ii][f] = ent[(node0 + ii)*128 + f]; }
  if (t < 4) nn_s[t] = cnt[node0 + t] & 0xffff;   // true neighbor count
  __syncthreads();
  int w = t >> 6, lane = t & 63;
  int ii = w >> 1, par = w & 1;
  float pia = pis[ii][2*lane]     + be1[2*lane];
  float pib = pis[ii][2*lane + 1] + be1[2*lane + 1];
  float a0 = 0.f, a1 = 0.f;
  int nn = nn_s[ii];
  for (int e = par; e < nn; e += 2) {
    unsigned int u = ent_s[ii][e];
    int j = u & 127;
    unsigned int hv = pjs[j*64 + lane];
    a0 += sspf(pia + bflo(hv));
    a1 += sspf(pib + bfhi(hv));
  }
  *(float2*)&sred[w][2*lane] = make_float2(a0, a1);
  __syncthreads();
  { int i2 = t >> 7, f = t & 127;
    s_s[i2][f] = sred[2*i2][f] + sred[2*i2+1][f]; }
  __syncthreads();
  { int i2 = t >> 7, o = t & 15, seg = (t >> 4) & 7;
    float p = 0.f;
    for (int f = seg*16; f < seg*16 + 16; f++) p += s_s[i2][f] * We2[f*16 + o];
    r2[i2][seg][o] = p; }
  __syncthreads();
  if (t < 64) {
    int i2 = t >> 4, o = t & 15;
    float v = be2[o] * (float)nn_s[i2];
    for (int seg = 0; seg < 8; seg++) v += r2[i2][seg][o];
    out[(node0 + i2)*16 + o] = v;
  }
}

// ---------------------------------------------------------------------------
extern "C" void kernel_launch(void* const* d_in, const int* in_sizes, int n_in,
                              void* d_out, int out_size, void* d_ws, size_t ws_size,
                              hipStream_t stream) {
  const float* coords = (const float*)d_in[0];
  const int*   species= (const int*)  d_in[1];
  const float* emb    = (const float*)d_in[2];
  const float* Wc1    = (const float*)d_in[3];
  const float* bc1    = (const float*)d_in[4];
  const float* Wc2    = (const float*)d_in[5];
  const float* bc2    = (const float*)d_in[6];
  const float* Wu1    = (const float*)d_in[7];
  const float* bu1    = (const float*)d_in[8];
  const float* Wu2    = (const float*)d_in[9];
  const float* bu2    = (const float*)d_in[10];
  const float* Wp1    = (const float*)d_in[11];
  const float* bp1    = (const float*)d_in[12];
  const float* Wp2    = (const float*)d_in[13];
  const float* bp2    = (const float*)d_in[14];
  const float* Wei    = (const float*)d_in[15];
  const float* Wej    = (const float*)d_in[16];
  const float* be1    = (const float*)d_in[17];
  const float* We2    = (const float*)d_in[18];
  const float* be2    = (const float*)d_in[19];
  float* out = (float*)d_out;

  float* wsf   = (float*)d_ws;
  float* table = wsf;                       //  4097*128 = 524416
  float* h_a   = wsf + 524416;              //  2048*128
  float* h_b   = wsf + 786560;
  float* pre_i = wsf + 1048704;
  float* pre_j = wsf + 1310848;
  unsigned int* ent = (unsigned int*)(wsf + 1572992);   // 2048*128
  int*          cnt = (int*)(wsf + 1835136);            // 2048
  (void)in_sizes; (void)n_in; (void)out_size; (void)ws_size;

  prep_kernel<<<1280, 256, 0, stream>>>(coords, species, emb, Wc1, bc1, Wc2, bc2,
                                        table, h_a, ent, cnt);
  conv_kernel<<<512, 512, 0, stream>>>(h_a, h_b, table, ent, cnt, Wu1, bu1, Wu2, bu2);
  conv_kernel<<<512, 512, 0, stream>>>(h_b, h_a, table, ent, cnt, Wu1, bu1, Wu2, bu2);
  conv_kernel<<<512, 512, 0, stream>>>(h_a, h_b, table, ent, cnt, Wu1, bu1, Wu2, bu2);
  poolpre_kernel<<<768, 256, 0, stream>>>(h_b, Wp1, bp1, Wp2, bp2, Wei, Wej,
                                          pre_i, pre_j, out);
  edgepool_kernel<<<512, 512, 0, stream>>>(pre_i, pre_j, ent, cnt, be1, We2, be2,
                                           out + 16384);
}